// Round 4
// baseline (737.572 us; speedup 1.0000x reference)
//
#include <hip/hip_runtime.h>
#include <hip/hip_bf16.h>

#define D 64

// ---------------------------------------------------------------------------
__global__ void out_init_kernel(float* __restrict__ out, const float* __restrict__ bout, int G) {
    int i = blockIdx.x * blockDim.x + threadIdx.x;
    if (i < G) out[i] = bout[0];
}

// ---------------------------------------------------------------------------
// CSR build: histogram -> scan -> scatter(pos) -> reorder ea (bf16)
// ---------------------------------------------------------------------------
__global__ void deg_hist_kernel(const int* __restrict__ ei, int* __restrict__ deg, int E) {
    int e = blockIdx.x * blockDim.x + threadIdx.x;
    if (e < E) atomicAdd(&deg[ei[E + e]], 1);
}

__global__ __launch_bounds__(1024) void scan1_kernel(
    const int* __restrict__ deg, int* __restrict__ off, int* __restrict__ bsum, int N)
{
    __shared__ int sh[1024];
    int t = threadIdx.x;
    int i = blockIdx.x * 1024 + t;
    int v = (i < N) ? deg[i] : 0;
    sh[t] = v;
    __syncthreads();
#pragma unroll
    for (int o = 1; o < 1024; o <<= 1) {
        int u = (t >= o) ? sh[t - o] : 0;
        __syncthreads();
        sh[t] += u;
        __syncthreads();
    }
    if (i < N) off[i] = sh[t] - v;
    if (t == 1023) bsum[blockIdx.x] = sh[t];
}

__global__ __launch_bounds__(128) void scan2_kernel(
    const int* __restrict__ bsum, int* __restrict__ boff, int nb)
{
    __shared__ int sh[128];
    int t = threadIdx.x;
    int v = (t < nb) ? bsum[t] : 0;
    sh[t] = v;
    __syncthreads();
#pragma unroll
    for (int o = 1; o < 128; o <<= 1) {
        int u = (t >= o) ? sh[t - o] : 0;
        __syncthreads();
        sh[t] += u;
        __syncthreads();
    }
    if (t < nb) boff[t] = sh[t] - v;
}

__global__ void scan3_kernel(int* __restrict__ off, const int* __restrict__ boff, int N) {
    int i = blockIdx.x * blockDim.x + threadIdx.x;
    if (i < N) off[i] += boff[i >> 10];
}

// pos[e] = CSR slot of edge e; src_csr[p] = src node; eid_csr[p] = e (fallback)
__global__ void scatter_kernel(const int* __restrict__ ei, const int* __restrict__ off,
                               int* __restrict__ cur, int* __restrict__ src_csr,
                               int* __restrict__ eid_csr, int* __restrict__ pos, int E)
{
    int e = blockIdx.x * blockDim.x + threadIdx.x;
    if (e >= E) return;
    int d = ei[E + e];
    int p = off[d] + atomicAdd(&cur[d], 1);
    src_csr[p] = ei[e];
    eid_csr[p] = e;
    pos[e] = p;
}

// sequential ea read, scattered bf16 row write: ea_csr[pos[e]] = bf16(ea[e])
__global__ __launch_bounds__(256) void reorder_kernel(
    const float* __restrict__ ea, const int* __restrict__ pos,
    __hip_bfloat16* __restrict__ ea_csr, int E)
{
    const int lane = threadIdx.x & 63;
    const int e    = (blockIdx.x << 2) + (threadIdx.x >> 6);
    if (e >= E) return;
    float v = ea[(size_t)e * D + lane];          // coalesced sequential 256B
    int p = pos[e];
    ea_csr[(size_t)p * D + lane] = __float2bfloat16(v);  // posted 128B scatter
}

// ---------------------------------------------------------------------------
// aggregate: one wave per node.  h[n] = x[n] + sum_e relu(x[src] + ea[e])
// REORD=1: ea_csr bf16 stream, fully sequential.  REORD=0: eid indirection.
// ---------------------------------------------------------------------------
template <int REORD>
__global__ __launch_bounds__(256) void aggregate_kernel(
    const float* __restrict__ xin, const float* __restrict__ ea,
    const __hip_bfloat16* __restrict__ ea_csr,
    const int* __restrict__ src_csr, const int* __restrict__ eid_csr,
    const int* __restrict__ off, const int* __restrict__ deg,
    float* __restrict__ h, int N)
{
    const int lane = threadIdx.x & 63;
    const int n    = (blockIdx.x << 2) + (threadIdx.x >> 6);
    if (n >= N) return;

    float self = xin[(size_t)n * D + lane];
    int p  = off[n];
    const int pe = p + deg[n];

    float a0 = 0.f, a1 = 0.f, a2 = 0.f, a3 = 0.f;
    for (; p + 3 < pe; p += 4) {
        int s0 = src_csr[p], s1 = src_csr[p + 1], s2 = src_csr[p + 2], s3 = src_csr[p + 3];
        float q0, q1, q2, q3;
        if (REORD) {
            q0 = __bfloat162float(ea_csr[(size_t)(p + 0) * D + lane]);
            q1 = __bfloat162float(ea_csr[(size_t)(p + 1) * D + lane]);
            q2 = __bfloat162float(ea_csr[(size_t)(p + 2) * D + lane]);
            q3 = __bfloat162float(ea_csr[(size_t)(p + 3) * D + lane]);
        } else {
            q0 = ea[(size_t)eid_csr[p + 0] * D + lane];
            q1 = ea[(size_t)eid_csr[p + 1] * D + lane];
            q2 = ea[(size_t)eid_csr[p + 2] * D + lane];
            q3 = ea[(size_t)eid_csr[p + 3] * D + lane];
        }
        float x0 = xin[(size_t)s0 * D + lane];
        float x1 = xin[(size_t)s1 * D + lane];
        float x2 = xin[(size_t)s2 * D + lane];
        float x3 = xin[(size_t)s3 * D + lane];
        a0 += fmaxf(x0 + q0, 0.f);
        a1 += fmaxf(x1 + q1, 0.f);
        a2 += fmaxf(x2 + q2, 0.f);
        a3 += fmaxf(x3 + q3, 0.f);
    }
    for (; p < pe; ++p) {
        int s0 = src_csr[p];
        float q0 = REORD ? __bfloat162float(ea_csr[(size_t)p * D + lane])
                         : ea[(size_t)eid_csr[p] * D + lane];
        a0 += fmaxf(xin[(size_t)s0 * D + lane] + q0, 0.f);
    }

    h[(size_t)n * D + lane] = self + ((a0 + a1) + (a2 + a3));
}

// ---------------------------------------------------------------------------
// MLP: relu(relu(h@W1+b1)@W2+b2). Weights pinned in VGPRs; wave-local LDS
// broadcast; 4 partial accumulators. LAST=1 fuses pool + Wout.
// ---------------------------------------------------------------------------
template <int LAST>
__global__ __launch_bounds__(256, 1) void mlp_kernel(
    const float* __restrict__ hin, float* __restrict__ xout,
    const float* __restrict__ W1, const float* __restrict__ b1,
    const float* __restrict__ W2, const float* __restrict__ b2,
    const int* __restrict__ batch, const float* __restrict__ Wout,
    float* __restrict__ out, int N, int chunk)
{
    __shared__ __align__(16) float sh[4][D];
    __shared__ __align__(16) float sh2[4][D];

    const int lane = threadIdx.x & 63;
    const int wid  = threadIdx.x >> 6;

    float w1[D], w2[D];
#pragma unroll
    for (int k = 0; k < D; ++k) w1[k] = W1[k * D + lane];
#pragma unroll
    for (int k = 0; k < D; ++k) w2[k] = W2[k * D + lane];
#pragma unroll
    for (int k = 0; k < D; ++k) { asm volatile("" : "+v"(w1[k])); asm volatile("" : "+v"(w2[k])); }
    const float b1l = b1[lane];
    const float b2l = b2[lane];
    const float wo  = LAST ? Wout[lane] : 0.f;

    const int w = (blockIdx.x << 2) + wid;
    int n0 = w * chunk;
    if (n0 >= N) return;
    int n1 = min(n0 + chunk, N);

    float gsum = 0.f;
    int   curg = -1;

    for (int n = n0; n < n1; ++n) {
        float hv = hin[(size_t)n * D + lane];
        sh[wid][lane] = hv;

        float t0 = 0.f, t1 = 0.f, t2 = 0.f, t3 = 0.f;
#pragma unroll
        for (int k = 0; k < D; k += 4) {
            float4 hk = *(const float4*)&sh[wid][k];
            t0 = fmaf(hk.x, w1[k + 0], t0);
            t1 = fmaf(hk.y, w1[k + 1], t1);
            t2 = fmaf(hk.z, w1[k + 2], t2);
            t3 = fmaf(hk.w, w1[k + 3], t3);
        }
        float hid = fmaxf(((t0 + t1) + (t2 + t3)) + b1l, 0.f);
        sh2[wid][lane] = hid;

        float s0 = 0.f, s1 = 0.f, s2 = 0.f, s3 = 0.f;
#pragma unroll
        for (int k = 0; k < D; k += 4) {
            float4 hk = *(const float4*)&sh2[wid][k];
            s0 = fmaf(hk.x, w2[k + 0], s0);
            s1 = fmaf(hk.y, w2[k + 1], s1);
            s2 = fmaf(hk.z, w2[k + 2], s2);
            s3 = fmaf(hk.w, w2[k + 3], s3);
        }
        float r = fmaxf(((s0 + s1) + (s2 + s3)) + b2l, 0.f);

        if (LAST) {
            float s = r * wo;
#pragma unroll
            for (int o = 32; o; o >>= 1) s += __shfl_xor(s, o, 64);
            int g = batch[n];
            if (g != curg) {
                if (curg >= 0 && lane == 0) atomicAdd(&out[curg], gsum);
                curg = g;
                gsum = s;
            } else {
                gsum += s;
            }
        } else {
            xout[(size_t)n * D + lane] = r;
        }
    }
    if (LAST && curg >= 0 && lane == 0) atomicAdd(&out[curg], gsum);
}

// ---------------------------------------------------------------------------
extern "C" void kernel_launch(void* const* d_in, const int* in_sizes, int n_in,
                              void* d_out, int out_size, void* d_ws, size_t ws_size,
                              hipStream_t stream) {
    const float* x     = (const float*)d_in[0];
    const int*   ei    = (const int*)d_in[1];
    const float* ea    = (const float*)d_in[2];
    const int*   batch = (const int*)d_in[3];
    const float* W1    = (const float*)d_in[4];
    const float* b1    = (const float*)d_in[5];
    const float* W2    = (const float*)d_in[6];
    const float* b2    = (const float*)d_in[7];
    const float* Wout  = (const float*)d_in[8];
    const float* bout  = (const float*)d_in[9];
    float* out = (float*)d_out;

    const int N = in_sizes[0] / D;   // 100000
    const int E = in_sizes[1] / 2;   // 1200000
    const int G = out_size;          // 128

    // ---- workspace layout (ea_csr last so the fallback needs less) ----
    char* w = (char*)d_ws;
    const size_t nodeBytes = (size_t)N * D * sizeof(float);
    float* bufA    = (float*)w;            w += nodeBytes;
    float* bufB    = (float*)w;            w += nodeBytes;
    int*   src_csr = (int*)w;              w += (size_t)E * sizeof(int);
    int*   eid_csr = (int*)w;              w += (size_t)E * sizeof(int);
    int*   pos     = (int*)w;              w += (size_t)E * sizeof(int);
    int*   deg     = (int*)w;              w += (size_t)N * sizeof(int);
    int*   off     = (int*)w;              w += (size_t)N * sizeof(int);
    int*   cur     = (int*)w;              w += (size_t)N * sizeof(int);
    int*   bsum    = (int*)w;              w += 128 * sizeof(int);
    int*   boff    = (int*)w;              w += 128 * sizeof(int);
    __hip_bfloat16* ea_csr = (__hip_bfloat16*)w;
    const size_t needBytes = (size_t)(w - (char*)d_ws) + (size_t)E * D * sizeof(__hip_bfloat16);
    const bool reord = (ws_size >= needBytes);

    const int nScanBlocks = (N + 1023) / 1024;
    const int edgeBlocks  = (E + 255) / 256;
    const int waveBlocksE = (E + 3) / 4;       // one wave per edge
    const int aggBlocks   = (N + 3) / 4;       // one wave per node

    const int mlpWaves  = 4096;
    const int mlpBlocks = mlpWaves / 4;
    const int chunk     = (N + mlpWaves - 1) / mlpWaves;

    out_init_kernel<<<(G + 127) / 128, 128, 0, stream>>>(out, bout, G);

    // ---- CSR build (shared by all layers) ----
    hipMemsetAsync(deg, 0, (size_t)N * sizeof(int), stream);
    hipMemsetAsync(cur, 0, (size_t)N * sizeof(int), stream);
    deg_hist_kernel<<<edgeBlocks, 256, 0, stream>>>(ei, deg, E);
    scan1_kernel<<<nScanBlocks, 1024, 0, stream>>>(deg, off, bsum, N);
    scan2_kernel<<<1, 128, 0, stream>>>(bsum, boff, nScanBlocks);
    scan3_kernel<<<(N + 255) / 256, 256, 0, stream>>>(off, boff, N);
    scatter_kernel<<<edgeBlocks, 256, 0, stream>>>(ei, off, cur, src_csr, eid_csr, pos, E);
    if (reord)
        reorder_kernel<<<waveBlocksE, 256, 0, stream>>>(ea, pos, ea_csr, E);

    // ---- 3 layers ----
    const float* xin = x;
    float* hb[3] = {bufA, bufB, bufA};
    for (int l = 0; l < 3; ++l) {
        if (reord)
            aggregate_kernel<1><<<aggBlocks, 256, 0, stream>>>(xin, ea, ea_csr,
                src_csr, eid_csr, off, deg, hb[l], N);
        else
            aggregate_kernel<0><<<aggBlocks, 256, 0, stream>>>(xin, ea, ea_csr,
                src_csr, eid_csr, off, deg, hb[l], N);
        if (l < 2) {
            mlp_kernel<0><<<mlpBlocks, 256, 0, stream>>>(hb[l], hb[l],
                W1 + l * D * D, b1 + l * D, W2 + l * D * D, b2 + l * D,
                batch, Wout, out, N, chunk);
            xin = hb[l];
        } else {
            mlp_kernel<1><<<mlpBlocks, 256, 0, stream>>>(hb[l], nullptr,
                W1 + l * D * D, b1 + l * D, W2 + l * D * D, b2 + l * D,
                batch, Wout, out, N, chunk);
        }
    }
}

// Round 5
// 606.042 us; speedup vs baseline: 1.2170x; 1.2170x over previous
//
#include <hip/hip_runtime.h>
#include <hip/hip_bf16.h>

#define D 64

typedef unsigned short u16;

static __device__ __forceinline__ u16 f2bf(float f) {
    unsigned u = __float_as_uint(f);
    unsigned r = (u + 0x7FFFu + ((u >> 16) & 1u)) >> 16;   // RNE
    return (u16)r;
}
static __device__ __forceinline__ float bf2f(u16 h) {
    return __uint_as_float(((unsigned)h) << 16);
}

// ---------------------------------------------------------------------------
__global__ void out_init_kernel(float* __restrict__ out, const float* __restrict__ bout, int G) {
    int i = blockIdx.x * blockDim.x + threadIdx.x;
    if (i < G) out[i] = bout[0];
}

// ---------------------------------------------------------------------------
// CSR build: histogram -> scan
// ---------------------------------------------------------------------------
__global__ void deg_hist_kernel(const int* __restrict__ ei, int* __restrict__ deg, int E) {
    int e = blockIdx.x * blockDim.x + threadIdx.x;
    if (e < E) atomicAdd(&deg[ei[E + e]], 1);
}

__global__ __launch_bounds__(1024) void scan1_kernel(
    const int* __restrict__ deg, int* __restrict__ off, int* __restrict__ bsum, int N)
{
    __shared__ int sh[1024];
    int t = threadIdx.x;
    int i = blockIdx.x * 1024 + t;
    int v = (i < N) ? deg[i] : 0;
    sh[t] = v;
    __syncthreads();
#pragma unroll
    for (int o = 1; o < 1024; o <<= 1) {
        int u = (t >= o) ? sh[t - o] : 0;
        __syncthreads();
        sh[t] += u;
        __syncthreads();
    }
    if (i < N) off[i] = sh[t] - v;
    if (t == 1023) bsum[blockIdx.x] = sh[t];
}

__global__ __launch_bounds__(128) void scan2_kernel(
    const int* __restrict__ bsum, int* __restrict__ boff, int nb)
{
    __shared__ int sh[128];
    int t = threadIdx.x;
    int v = (t < nb) ? bsum[t] : 0;
    sh[t] = v;
    __syncthreads();
#pragma unroll
    for (int o = 1; o < 128; o <<= 1) {
        int u = (t >= o) ? sh[t - o] : 0;
        __syncthreads();
        sh[t] += u;
        __syncthreads();
    }
    if (t < nb) boff[t] = sh[t] - v;
}

__global__ void scan3_kernel(int* __restrict__ off, const int* __restrict__ boff, int N) {
    int i = blockIdx.x * blockDim.x + threadIdx.x;
    if (i < N) off[i] += boff[i >> 10];
}

// ---------------------------------------------------------------------------
// build: fused scatter + reorder.  Wave handles 4 edges, 16 lanes/edge.
// Sequential fp32 ea read (1 KB/wave contiguous), bf16 row write to CSR slot.
// ---------------------------------------------------------------------------
__global__ __launch_bounds__(256) void build_kernel(
    const float* __restrict__ ea, const int* __restrict__ ei,
    const int* __restrict__ off, int* __restrict__ cur,
    int* __restrict__ src_csr, u16* __restrict__ ea_csr, int E)
{
    const int lane = threadIdx.x & 63;
    const int q = lane & 15, g = lane >> 4;
    const long long wv = (long long)blockIdx.x * 4 + (threadIdx.x >> 6);
    const int e = (int)(wv * 4) + g;

    int p = 0, s = 0;
    if (e < E && q == 0) {
        int d = ei[E + e];
        s = ei[e];
        p = off[d] + atomicAdd(&cur[d], 1);
    }
    p = __shfl(p, lane & 48, 64);        // broadcast group leader's slot
    if (e >= E) return;

    float4 v = *(const float4*)&ea[(size_t)e * D + q * 4];
    u16 b0 = f2bf(v.x), b1 = f2bf(v.y), b2 = f2bf(v.z), b3 = f2bf(v.w);
    u16* dst = &ea_csr[(size_t)p * D + q * 4];
    dst[0] = b0; dst[1] = b1; dst[2] = b2; dst[3] = b3;   // one 8B store after SLP
    if (q == 0) src_csr[p] = s;
}

// ---------------------------------------------------------------------------
// aggregate: wave per node, 16 lanes/edge, 4 edges in flight.
// h[n] = x[n] + sum_e relu(x[src] + ea[e]); ea stream is sequential bf16.
// ---------------------------------------------------------------------------
__global__ __launch_bounds__(256) void aggregate_kernel(
    const float* __restrict__ xin, const u16* __restrict__ ea_csr,
    const int* __restrict__ src_csr, const int* __restrict__ off,
    const int* __restrict__ deg, float* __restrict__ h, int N)
{
    const int lane = threadIdx.x & 63;
    const int q = lane & 15, g = lane >> 4;
    const int n = (blockIdx.x << 2) + (threadIdx.x >> 6);
    if (n >= N) return;

    int p = off[n];
    const int pe = p + deg[n];

    float a0 = 0.f, a1 = 0.f, a2 = 0.f, a3 = 0.f;
    for (; p + 4 <= pe; p += 4) {
        int s = src_csr[p + g];
        const u16* eb = &ea_csr[(size_t)(p + g) * D + q * 4];
        u16 e0 = eb[0], e1 = eb[1], e2 = eb[2], e3 = eb[3];
        float4 xv = *(const float4*)&xin[(size_t)s * D + q * 4];
        a0 += fmaxf(xv.x + bf2f(e0), 0.f);
        a1 += fmaxf(xv.y + bf2f(e1), 0.f);
        a2 += fmaxf(xv.z + bf2f(e2), 0.f);
        a3 += fmaxf(xv.w + bf2f(e3), 0.f);
    }
    const int rem = pe - p;
    if (g < rem) {
        int s = src_csr[p + g];
        const u16* eb = &ea_csr[(size_t)(p + g) * D + q * 4];
        u16 e0 = eb[0], e1 = eb[1], e2 = eb[2], e3 = eb[3];
        float4 xv = *(const float4*)&xin[(size_t)s * D + q * 4];
        a0 += fmaxf(xv.x + bf2f(e0), 0.f);
        a1 += fmaxf(xv.y + bf2f(e1), 0.f);
        a2 += fmaxf(xv.z + bf2f(e2), 0.f);
        a3 += fmaxf(xv.w + bf2f(e3), 0.f);
    }

    // reduce over the 4 edge-groups (dims are per-q, groups differ only in edges)
    a0 += __shfl_xor(a0, 16, 64);  a1 += __shfl_xor(a1, 16, 64);
    a2 += __shfl_xor(a2, 16, 64);  a3 += __shfl_xor(a3, 16, 64);
    a0 += __shfl_xor(a0, 32, 64);  a1 += __shfl_xor(a1, 32, 64);
    a2 += __shfl_xor(a2, 32, 64);  a3 += __shfl_xor(a3, 32, 64);

    float4 xs = *(const float4*)&xin[(size_t)n * D + q * 4];
    if (lane < 16) {
        float4 o;
        o.x = a0 + xs.x; o.y = a1 + xs.y; o.z = a2 + xs.z; o.w = a3 + xs.w;
        *(float4*)&h[(size_t)n * D + q * 4] = o;
    }
}

// ---------------------------------------------------------------------------
// MLP: relu(relu(h@W1+b1)@W2+b2). Weights pinned in VGPRs; wave-local LDS
// broadcast; 4 partial accumulators. LAST=1 fuses pool + Wout.
// ---------------------------------------------------------------------------
template <int LAST>
__global__ __launch_bounds__(256, 1) void mlp_kernel(
    const float* __restrict__ hin, float* __restrict__ xout,
    const float* __restrict__ W1, const float* __restrict__ b1,
    const float* __restrict__ W2, const float* __restrict__ b2,
    const int* __restrict__ batch, const float* __restrict__ Wout,
    float* __restrict__ out, int N, int chunk)
{
    __shared__ __align__(16) float sh[4][D];
    __shared__ __align__(16) float sh2[4][D];

    const int lane = threadIdx.x & 63;
    const int wid  = threadIdx.x >> 6;

    float w1[D], w2[D];
#pragma unroll
    for (int k = 0; k < D; ++k) w1[k] = W1[k * D + lane];
#pragma unroll
    for (int k = 0; k < D; ++k) w2[k] = W2[k * D + lane];
#pragma unroll
    for (int k = 0; k < D; ++k) { asm volatile("" : "+v"(w1[k])); asm volatile("" : "+v"(w2[k])); }
    const float b1l = b1[lane];
    const float b2l = b2[lane];
    const float wo  = LAST ? Wout[lane] : 0.f;

    const int w = (blockIdx.x << 2) + wid;
    int n0 = w * chunk;
    if (n0 >= N) return;
    int n1 = min(n0 + chunk, N);

    float gsum = 0.f;
    int   curg = -1;

    for (int n = n0; n < n1; ++n) {
        float hv = hin[(size_t)n * D + lane];
        sh[wid][lane] = hv;

        float t0 = 0.f, t1 = 0.f, t2 = 0.f, t3 = 0.f;
#pragma unroll
        for (int k = 0; k < D; k += 4) {
            float4 hk = *(const float4*)&sh[wid][k];
            t0 = fmaf(hk.x, w1[k + 0], t0);
            t1 = fmaf(hk.y, w1[k + 1], t1);
            t2 = fmaf(hk.z, w1[k + 2], t2);
            t3 = fmaf(hk.w, w1[k + 3], t3);
        }
        float hid = fmaxf(((t0 + t1) + (t2 + t3)) + b1l, 0.f);
        sh2[wid][lane] = hid;

        float s0 = 0.f, s1 = 0.f, s2 = 0.f, s3 = 0.f;
#pragma unroll
        for (int k = 0; k < D; k += 4) {
            float4 hk = *(const float4*)&sh2[wid][k];
            s0 = fmaf(hk.x, w2[k + 0], s0);
            s1 = fmaf(hk.y, w2[k + 1], s1);
            s2 = fmaf(hk.z, w2[k + 2], s2);
            s3 = fmaf(hk.w, w2[k + 3], s3);
        }
        float r = fmaxf(((s0 + s1) + (s2 + s3)) + b2l, 0.f);

        if (LAST) {
            float s = r * wo;
#pragma unroll
            for (int o = 32; o; o >>= 1) s += __shfl_xor(s, o, 64);
            int g = batch[n];
            if (g != curg) {
                if (curg >= 0 && lane == 0) atomicAdd(&out[curg], gsum);
                curg = g;
                gsum = s;
            } else {
                gsum += s;
            }
        } else {
            xout[(size_t)n * D + lane] = r;
        }
    }
    if (LAST && curg >= 0 && lane == 0) atomicAdd(&out[curg], gsum);
}

// ---------------------------------------------------------------------------
extern "C" void kernel_launch(void* const* d_in, const int* in_sizes, int n_in,
                              void* d_out, int out_size, void* d_ws, size_t ws_size,
                              hipStream_t stream) {
    const float* x     = (const float*)d_in[0];
    const int*   ei    = (const int*)d_in[1];
    const float* ea    = (const float*)d_in[2];
    const int*   batch = (const int*)d_in[3];
    const float* W1    = (const float*)d_in[4];
    const float* b1    = (const float*)d_in[5];
    const float* W2    = (const float*)d_in[6];
    const float* b2    = (const float*)d_in[7];
    const float* Wout  = (const float*)d_in[8];
    const float* bout  = (const float*)d_in[9];
    float* out = (float*)d_out;

    const int N = in_sizes[0] / D;   // 100000
    const int E = in_sizes[1] / 2;   // 1200000
    const int G = out_size;          // 128

    // ---- workspace layout ----
    char* w = (char*)d_ws;
    const size_t nodeBytes = (size_t)N * D * sizeof(float);
    float* bufA    = (float*)w;            w += nodeBytes;
    float* bufB    = (float*)w;            w += nodeBytes;
    int*   src_csr = (int*)w;              w += (size_t)E * sizeof(int);
    int*   deg     = (int*)w;              w += (size_t)N * sizeof(int);
    int*   off     = (int*)w;              w += (size_t)N * sizeof(int);
    int*   cur     = (int*)w;              w += (size_t)N * sizeof(int);
    int*   bsum    = (int*)w;              w += 128 * sizeof(int);
    int*   boff    = (int*)w;              w += 128 * sizeof(int);
    u16*   ea_csr  = (u16*)w;              // E*D*2 bytes

    const int nScanBlocks = (N + 1023) / 1024;
    const int edgeBlocks  = (E + 255) / 256;
    const int buildBlocks = (E + 15) / 16;     // 4 waves * 4 edges per block
    const int aggBlocks   = (N + 3) / 4;       // one wave per node

    const int mlpWaves  = 4096;
    const int mlpBlocks = mlpWaves / 4;
    const int chunk     = (N + mlpWaves - 1) / mlpWaves;

    out_init_kernel<<<(G + 127) / 128, 128, 0, stream>>>(out, bout, G);

    // ---- CSR build + bf16 edge reorder (shared by all layers) ----
    hipMemsetAsync(deg, 0, (size_t)N * sizeof(int), stream);
    hipMemsetAsync(cur, 0, (size_t)N * sizeof(int), stream);
    deg_hist_kernel<<<edgeBlocks, 256, 0, stream>>>(ei, deg, E);
    scan1_kernel<<<nScanBlocks, 1024, 0, stream>>>(deg, off, bsum, N);
    scan2_kernel<<<1, 128, 0, stream>>>(bsum, boff, nScanBlocks);
    scan3_kernel<<<(N + 255) / 256, 256, 0, stream>>>(off, boff, N);
    build_kernel<<<buildBlocks, 256, 0, stream>>>(ea, ei, off, cur, src_csr, ea_csr, E);

    // ---- 3 layers ----
    const float* xin = x;
    float* hb[3] = {bufA, bufB, bufA};
    for (int l = 0; l < 3; ++l) {
        aggregate_kernel<<<aggBlocks, 256, 0, stream>>>(xin, ea_csr, src_csr, off, deg, hb[l], N);
        if (l < 2) {
            mlp_kernel<0><<<mlpBlocks, 256, 0, stream>>>(hb[l], hb[l],
                W1 + l * D * D, b1 + l * D, W2 + l * D * D, b2 + l * D,
                batch, Wout, out, N, chunk);
            xin = hb[l];
        } else {
            mlp_kernel<1><<<mlpBlocks, 256, 0, stream>>>(hb[l], nullptr,
                W1 + l * D * D, b1 + l * D, W2 + l * D * D, b2 + l * D,
                batch, Wout, out, N, chunk);
        }
    }
}